// Round 2
// baseline (30413.879 us; speedup 1.0000x reference)
//
#include <hip/hip_runtime.h>
#include <math.h>

#define NN 32
#define PADL 36   // L buffer column stride (f32), keeps float4 chunks 16B aligned
#define PADT 33   // transpose buffer column stride, bank-conflict-free b32
#define NSWEEP 6

// ---------------- one-sided Jacobi (XOR cyclic ordering) ----------------
// g[]: this lane's column of a 32x32 SPD matrix (lane l5 of each 32-half owns col l5).
// On exit: g[] = (eigvec_j * lambda_j) columns, nrm = lambda_j^2 (exact recompute).
__device__ __forceinline__ void jacobi_sweeps(float g[NN], float &nrm) {
  const int lane = threadIdx.x;
  {
    float a0=0.f,a1=0.f,a2=0.f,a3=0.f;
    #pragma unroll
    for (int i = 0; i < NN; i += 4) {
      a0 = fmaf(g[i+0],g[i+0],a0); a1 = fmaf(g[i+1],g[i+1],a1);
      a2 = fmaf(g[i+2],g[i+2],a2); a3 = fmaf(g[i+3],g[i+3],a3);
    }
    nrm = (a0+a1)+(a2+a3);
  }
  #pragma unroll 1
  for (int sw = 0; sw < NSWEEP; ++sw) {
    #pragma unroll 1
    for (int m = 1; m < NN; ++m) {
      float p[NN];
      #pragma unroll
      for (int i = 0; i < NN; ++i) p[i] = __shfl_xor(g[i], m);
      float d0=0.f,d1=0.f,d2=0.f,d3=0.f;
      #pragma unroll
      for (int i = 0; i < NN; i += 4) {
        d0 = fmaf(g[i+0], p[i+0], d0); d1 = fmaf(g[i+1], p[i+1], d1);
        d2 = fmaf(g[i+2], p[i+2], d2); d3 = fmaf(g[i+3], p[i+3], d3);
      }
      float d = (d0+d1)+(d2+d3);
      float other = __shfl_xor(nrm, m);
      bool isP = (((lane ^ m) & 31) > (lane & 31));   // partner has higher index -> we are "p"
      // shared p-perspective quantities (identical on both lanes of the pair)
      float pn = isP ? nrm : other;
      float qn = isP ? other : nrm;
      float delta = pn - qn;
      float R   = sqrtf(fmaf(delta, delta, 4.f*d*d));
      float den = delta + copysignf(R + 1e-30f, delta);
      float t = -2.f*d / den;                  // small-|t| root of d t^2 - delta t - d = 0
      float c = rsqrtf(fmaf(t, t, 1.f));
      float s = t * c;
      float sg = isP ? -s : s;                 // p: c*gp - s*gq ; q: c*gq + s*gp
      #pragma unroll
      for (int i = 0; i < NN; ++i) g[i] = fmaf(sg, p[i], c*g[i]);
      float csd2 = 2.f*c*s*d;
      nrm = c*c*nrm + s*s*other + (isP ? -csd2 : csd2);
    }
  }
  // exact norm recompute (analytic updates drift slightly)
  float a0=0.f,a1=0.f,a2=0.f,a3=0.f;
  #pragma unroll
  for (int i = 0; i < NN; i += 4) {
    a0 = fmaf(g[i+0],g[i+0],a0); a1 = fmaf(g[i+1],g[i+1],a1);
    a2 = fmaf(g[i+2],g[i+2],a2); a3 = fmaf(g[i+3],g[i+3],a3);
  }
  nrm = (a0+a1)+(a2+a3);
}

// ---------------- Cholesky: m[] (col of SPD M, in place -> col of L) ----------------
// Writes L col-major into Lbuf (Lbuf[c*PADL + r] = L[r][c]) and 1/L[j][j] at Lbuf[j*PADL+32].
__device__ __forceinline__ void cholesky32(float m[NN], float *Lbuf, int l5) {
  #pragma unroll
  for (int j = 0; j < NN; ++j) {
    float bj   = __shfl(m[j], j, 32);      // current diagonal (Schur-complement) value
    float invd = rsqrtf(bj);               // 1/L[j][j]
    float lkj  = m[j] * invd;              // own L[lane][j] (valid for lanes >= j, by symmetry)
    bool isj = (l5 == j), gt = (l5 > j);
    #pragma unroll
    for (int i = j; i < NN; ++i) {
      float bi  = __shfl(m[i], j, 32);
      float lij = bi * invd;
      float upd = fmaf(-lij, lkj, m[i]);
      m[i] = isj ? lij : (gt ? upd : m[i]);
    }
    if (isj) Lbuf[j*PADL + 32] = invd;
  }
  #pragma unroll
  for (int i = 0; i < NN; i += 4)
    *(float4*)&Lbuf[l5*PADL + i] = make_float4(m[i], m[i+1], m[i+2], m[i+3]);
}

// ---------------- forward triangular solve: x := L^-1 x (x = lane-owned RHS column) ----
__device__ __forceinline__ void trsv32(float x[NN], const float *Lbuf) {
  #pragma unroll
  for (int j = 0; j < NN; ++j) {
    float yj = x[j] * Lbuf[j*PADL + 32];
    x[j] = yj;
    #pragma unroll
    for (int i0 = ((j+1) & ~3); i0 < NN; i0 += 4) {
      float4 Lc = *(const float4*)&Lbuf[j*PADL + i0];
      if (i0+0 > j) x[i0+0] = fmaf(-Lc.x, yj, x[i0+0]);
      if (i0+1 > j) x[i0+1] = fmaf(-Lc.y, yj, x[i0+1]);
      if (i0+2 > j) x[i0+2] = fmaf(-Lc.z, yj, x[i0+2]);
      if (i0+3 > j) x[i0+3] = fmaf(-Lc.w, yj, x[i0+3]);
    }
  }
}

// ---------------- 32x32 transpose of lane-owned columns via LDS ----------------
__device__ __forceinline__ void transpose32(float x[NN], float *Tbuf, int l5) {
  __syncthreads();
  #pragma unroll
  for (int i = 0; i < NN; ++i) Tbuf[l5*PADT + i] = x[i];
  __syncthreads();
  #pragma unroll
  for (int i = 0; i < NN; ++i) x[i] = Tbuf[i*PADT + l5];
}

// ---------------- z = L * us (L lower-tri from Lbuf, us lane-owned column) ----------
__device__ __forceinline__ void trmul_L(const float us[NN], float z[NN], const float *Lbuf) {
  #pragma unroll
  for (int i = 0; i < NN; ++i) z[i] = 0.f;
  #pragma unroll
  for (int k = 0; k < NN; ++k) {
    float uk = us[k];
    #pragma unroll
    for (int i0 = (k & ~3); i0 < NN; i0 += 4) {
      float4 Lc = *(const float4*)&Lbuf[k*PADL + i0];
      if (i0+0 >= k) z[i0+0] = fmaf(Lc.x, uk, z[i0+0]);
      if (i0+1 >= k) z[i0+1] = fmaf(Lc.y, uk, z[i0+1]);
      if (i0+2 >= k) z[i0+2] = fmaf(Lc.z, uk, z[i0+2]);
      if (i0+3 >= k) z[i0+3] = fmaf(Lc.w, uk, z[i0+3]);
    }
  }
}

// ---------------- out := Z * Z^T (Z = lane-owned columns), via LDS ----------------
__device__ __forceinline__ void zzT(const float z[NN], float out[NN], float *Tbuf, int l5) {
  __syncthreads();
  #pragma unroll
  for (int i = 0; i < NN; ++i) Tbuf[l5*PADT + i] = z[i];
  __syncthreads();
  #pragma unroll
  for (int i = 0; i < NN; ++i) out[i] = 0.f;
  #pragma unroll 1
  for (int k = 0; k < NN; ++k) {
    float zjk = Tbuf[k*PADT + l5];           // Z[l5][k] (vector read, conflict-free)
    #pragma unroll
    for (int i = 0; i < NN; ++i)
      out[i] = fmaf(Tbuf[k*PADT + i], zjk, out[i]);  // broadcast reads
  }
}

// ================= K0: weight tables =================
__global__ void k_tables(const float* __restrict__ W, float* __restrict__ tfwd,
                         float* __restrict__ trev, float* __restrict__ wnn) {
  int o = threadIdx.x;
  if (o >= NN) return;
  float w[NN];
  #pragma unroll 1
  for (int i = 0; i < NN; ++i) w[i] = fminf(fmaxf(W[o*NN+i], 0.001f), 0.999f);
  float cs = 0.f;
  #pragma unroll 1
  for (int i = 0; i < NN; ++i) { cs += w[i]; tfwd[o*NN+i] = w[i]/cs; }
  float tot = cs;
  #pragma unroll 1
  for (int i = 0; i < NN; ++i) wnn[o*NN+i] = w[i]/tot;
  cs = 0.f;
  #pragma unroll 1
  for (int i = 0; i < NN; ++i) { cs += w[NN-1-i]; trev[o*NN+i] = w[NN-1-i]/cs; }
}

// ================= K1: Llog[b,i] = logm(X[b,i]) =================
__global__ __launch_bounds__(64) void k_logm(const float* __restrict__ x,
                                             float* __restrict__ llog) {
  __shared__ float Tbuf[2][NN*PADT];
  int lane = threadIdx.x, half = lane >> 5, l5 = lane & 31;
  int P = blockIdx.x*2 + half;                  // b*I + i
  const float* xp = x + (size_t)P*1024 + l5;
  float g[NN];
  #pragma unroll
  for (int i = 0; i < NN; ++i) g[i] = xp[i*NN];
  float nrm;
  jacobi_sweeps(g, nrm);                        // X is SPD: sigma = lambda
  float lg   = 0.5f * log2f(fmaxf(nrm, 1e-12f)); // log2(lambda)
  float lnl  = lg * 0.69314718056f;              // ln(lambda)
  float invl = exp2f(-lg);                       // 1/lambda
  float *Tb = Tbuf[half];
  __syncthreads();
  #pragma unroll
  for (int i = 0; i < NN; ++i) Tb[l5*PADT + i] = g[i]*invl;   // U columns
  Tb[l5*PADT + 32] = lnl;
  __syncthreads();
  float m[NN];
  #pragma unroll
  for (int i = 0; i < NN; ++i) m[i] = 0.f;
  #pragma unroll 1
  for (int k = 0; k < NN; ++k) {
    float coef = Tb[k*PADT + 32] * Tb[k*PADT + l5];  // ln(lam_k) * U[l5][k]
    #pragma unroll
    for (int i = 0; i < NN; ++i) m[i] = fmaf(Tb[k*PADT + i], coef, m[i]);
  }
  float* op = llog + (size_t)P*1024 + l5;
  #pragma unroll
  for (int i = 0; i < NN; ++i) op[i*NN] = m[i];
}

// ================= K2: out3 = expm( sum_i wnn[o,i] * Llog[b,i] ) =================
__global__ __launch_bounds__(64) void k_fastfm(const float* __restrict__ llog,
                                               const float* __restrict__ wnn,
                                               float* __restrict__ out3) {
  __shared__ float Tbuf[2][NN*PADT];
  int lane = threadIdx.x, half = lane >> 5, l5 = lane & 31;
  int P = blockIdx.x*2 + half;                  // b*O + o
  int b = P >> 5, o = P & 31;
  float acc[NN];
  #pragma unroll
  for (int i = 0; i < NN; ++i) acc[i] = 0.f;
  const float* lp = llog + (size_t)b*NN*1024 + l5;
  #pragma unroll 1
  for (int i2 = 0; i2 < NN; ++i2) {
    float w = wnn[o*NN + i2];
    const float* q = lp + (size_t)i2*1024;
    #pragma unroll
    for (int i = 0; i < NN; ++i) acc[i] = fmaf(q[i*NN], w, acc[i]);
  }
  // shift by +4I so the matrix is SPD (log-eigs are in [-0.7, ~2.5]); expm(M)=e^-4 expm(M+4I)
  #pragma unroll
  for (int i = 0; i < NN; ++i) acc[i] += (i == l5) ? 4.0f : 0.0f;
  float nrm;
  jacobi_sweeps(acc, nrm);
  float lg  = 0.5f * log2f(fmaxf(nrm, 1e-12f));
  float lam = exp2f(lg);                        // shifted eigenvalue (lam_true + 4)
  float sc  = expf(0.5f*(lam - 4.0f)) * exp2f(-lg);  // exp(lam_true/2)/lam
  #pragma unroll
  for (int i = 0; i < NN; ++i) acc[i] *= sc;    // Us columns
  float m3[NN];
  zzT(acc, m3, Tbuf[half], l5);                 // Us Us^T
  float* op = out3 + (size_t)P*1024 + l5;
  #pragma unroll
  for (int i = 0; i < NN; ++i) op[i*NN] = m3[i];
}

// ================= K3: recursive Frechet mean scan (both directions) =================
__global__ __launch_bounds__(64) void k_recursive(const float* __restrict__ x,
    const float* __restrict__ tfwd, const float* __restrict__ trev,
    float* __restrict__ out1, float* __restrict__ out2) {
  __shared__ float Lbuf[2][NN*PADL];
  __shared__ float Tbuf[2][NN*PADT];
  int lane = threadIdx.x, half = lane >> 5, l5 = lane & 31;
  int P = blockIdx.x*2 + half;                  // 0..16383
  int dir = P >> 13;                            // B*O = 8192 per direction
  int rem = P & 8191;
  int b = rem >> 5, o = rem & 31;
  const float* tt = dir ? trev : tfwd;
  float* outp = (dir ? out2 : out1) + (size_t)(b*NN + o)*1024;
  const float* xb = x + (size_t)b*NN*1024;
  float *Lb = Lbuf[half], *Tb = Tbuf[half];

  float m[NN];
  {
    const float* xp = xb + (size_t)(dir ? (NN-1) : 0)*1024 + l5;
    #pragma unroll
    for (int i = 0; i < NN; ++i) m[i] = xp[i*NN];
  }
  #pragma unroll 1
  for (int j = 1; j < NN; ++j) {
    int k = dir ? (NN-1-j) : j;
    float xk[NN];
    const float* xp = xb + (size_t)k*1024 + l5;   // issue loads early; consumed after chol
    #pragma unroll
    for (int i = 0; i < NN; ++i) xk[i] = xp[i*NN];
    float tv = tt[o*NN + j];

    cholesky32(m, Lb, l5);                        // M = L L^T  (m[] -> L columns)

    // C = L^-1 X L^-T  via two forward solves + transpose (X symmetric)
    #pragma unroll 1
    for (int pass = 0; pass < 2; ++pass) {
      trsv32(xk, Lb);
      if (pass == 0) transpose32(xk, Tb, l5);
    }

    float nrm;
    jacobi_sweeps(xk, nrm);                       // C = U diag(lam) U^T, lam = sqrt(nrm)
    // us = U * lam^{t/2}  ==  g * lam^{t/2 - 1}
    float lg = 0.5f * log2f(fmaxf(nrm, 1e-12f));  // log2(lam)
    float sc = exp2f(lg * (0.5f*tv - 1.0f));
    #pragma unroll
    for (int i = 0; i < NN; ++i) xk[i] *= sc;

    float z[NN];
    trmul_L(xk, z, Lb);                           // Z = L * Us
    zzT(z, m, Tb, l5);                            // M' = Z Z^T  (= L C^t L^T, exactly sym)
  }
  #pragma unroll
  for (int i = 0; i < NN; ++i) outp[i*NN + l5] = m[i];
}

extern "C" void kernel_launch(void* const* d_in, const int* in_sizes, int n_in,
                              void* d_out, int out_size, void* d_ws, size_t ws_size,
                              hipStream_t stream) {
  (void)in_sizes; (void)n_in; (void)out_size; (void)ws_size;
  const float* x = (const float*)d_in[0];
  const float* W = (const float*)d_in[1];
  float* out  = (float*)d_out;
  float* ws   = (float*)d_ws;
  float* tfwd = ws;
  float* trev = ws + 1024;
  float* wnn  = ws + 2048;
  float* out1 = out;
  float* out2 = out + 8388608;
  float* out3 = out + 16777216;
  // llog scratch lives in out1's region: K1 writes it, K2 reads it, K3 overwrites
  // out1 afterwards (stream-ordered). Avoids any assumption about ws_size > 12 KiB.
  float* llog = out1;

  hipLaunchKernelGGL(k_tables,    dim3(1),    dim3(64), 0, stream, W, tfwd, trev, wnn);
  hipLaunchKernelGGL(k_logm,      dim3(4096), dim3(64), 0, stream, x, llog);
  hipLaunchKernelGGL(k_fastfm,    dim3(4096), dim3(64), 0, stream, llog, wnn, out3);
  hipLaunchKernelGGL(k_recursive, dim3(8192), dim3(64), 0, stream, x, tfwd, trev, out1, out2);
}